// Round 4
// baseline (548.997 us; speedup 1.0000x reference)
//
#include <hip/hip_runtime.h>
#include <math.h>

#define BATCH 128
#define ACT 7
#define NC 100
#define CTXD 128
#define HID 512
#define NROWS (BATCH*NC)     // 12800 per iteration
#define TROWS (6*NROWS)      // 76800 total candidate rows
#define QW 600               // q width (cols 600..699 of reference are exactly 0)

typedef __attribute__((ext_vector_type(8))) __bf16 bf16x8;
typedef __attribute__((ext_vector_type(4))) float f32x4;
typedef __attribute__((ext_vector_type(8))) unsigned short u16x8;
typedef __attribute__((ext_vector_type(4))) unsigned short u16x4;

__device__ __forceinline__ unsigned short f2bf(float f) {
    union { float f; unsigned int u; } v; v.f = f;
    unsigned int u = v.u;
    return (unsigned short)((u + 0x7fffu + ((u >> 16) & 1u)) >> 16);
}

// async global->LDS, 16B per lane. LDS dest = wave-uniform base + lane*16.
__device__ __forceinline__ void async16(const void* g, void* l) {
    __builtin_amdgcn_global_load_lds(
        (const __attribute__((address_space(1))) unsigned int*)(uintptr_t)g,
        (__attribute__((address_space(3))) unsigned int*)(unsigned int)(uintptr_t)l,
        16, 0, 0);
}

// ---------------- cvt: fp32 -> bf16 row-major copies -------------------------
// segments: obs(65536) | W1C rows 513..640 of W1[1..6] (6*65536) |
//           W2[1..6] (6*262144) | W3[1..6] (6*65536)
__global__ void cvt_kernel(const float* __restrict__ obs, const float* __restrict__ W1,
                           const float* __restrict__ W2, const float* __restrict__ W3,
                           unsigned short* __restrict__ obs_bf, unsigned short* __restrict__ W1Cbf,
                           unsigned short* __restrict__ W2bf, unsigned short* __restrict__ W3bf) {
    const int e = (blockIdx.x * 256 + threadIdx.x) * 4;   // grid covers 2424832 elems
    const float* src; unsigned short* dst;
    if (e < 65536)        { src = obs + e; dst = obs_bf + e; }
    else if (e < 458752)  { int f = e - 65536; int i = f >> 16; int rem = f & 65535;
                            src = W1 + (size_t)(i + 1) * 328192 + 513*512 + rem; dst = W1Cbf + f; }
    else if (e < 2031616) { int f = e - 458752; src = W2 + 262144 + f; dst = W2bf + f; }
    else                  { int f = e - 2031616; src = W3 + 65536 + f; dst = W3bf + f; }
    float4 v = *(const float4*)src;
    u16x4 o; o[0] = f2bf(v.x); o[1] = f2bf(v.y); o[2] = f2bf(v.z); o[3] = f2bf(v.w);
    *(u16x4*)dst = o;
}

// ---------------- transpose+convert: W1AT / W2T / W3T ------------------------
__global__ void prep_transpose(const float* __restrict__ W1, const float* __restrict__ W2,
                               const float* __restrict__ W3,
                               unsigned short* __restrict__ W1AT, unsigned short* __restrict__ W2T,
                               unsigned short* __restrict__ W3T) {
    __shared__ float tile[32][33];
    const int z = blockIdx.z;
    const float* ip; unsigned short* op; int Cn;
    if (z < 6)       { ip = W1 + (size_t)(z + 1) * 328192; op = W1AT + (size_t)z * 262144; Cn = 512; }
    else if (z < 12) { int i = z - 6;  ip = W2 + (size_t)(i + 1) * 262144; op = W2T + (size_t)i * 262144; Cn = 512; }
    else             { int i = z - 12; ip = W3 + (size_t)(i + 1) * 65536;  op = W3T + (size_t)i * 65536;  Cn = 128;
                       if (blockIdx.y >= 4) return; }
    const int r0 = blockIdx.x * 32, c0 = blockIdx.y * 32;
    const int tx = threadIdx.x, ty = threadIdx.y;  // 32 x 8
    #pragma unroll
    for (int j = 0; j < 32; j += 8)
        tile[ty + j][tx] = ip[(size_t)(r0 + ty + j) * Cn + c0 + tx];
    __syncthreads();
    #pragma unroll
    for (int j = 0; j < 32; j += 8)
        op[(size_t)(c0 + ty + j) * 512 + r0 + tx] = f2bf(tile[tx][ty + j]);
}

// ---------------- Yobs[z][b][h] = obs@W1A[z+1] + b1[z+1] ---------------------
__launch_bounds__(256)
__global__ void yobs_kernel(const unsigned short* __restrict__ A,      // obs_bf [128][512]
                            const unsigned short* __restrict__ BtAll,  // W1AT [6][512][512]
                            const float* __restrict__ b1,
                            float* __restrict__ Yobs) {
    __shared__ unsigned short As[64*32];
    __shared__ unsigned short Bs[128*32];
    const int m0 = blockIdx.x * 64;
    const int n0 = blockIdx.y * 128;
    const int z  = blockIdx.z;
    const unsigned short* Bt = BtAll + (size_t)z * 262144;
    const int tid = threadIdx.x, lane = tid & 63, wave = tid >> 6;
    const int wm = wave >> 1, wn = wave & 1;
    const int srow = tid >> 2, skc = (tid & 3) * 8;
    const unsigned short* gA  = A  + (size_t)(m0 + srow) * HID + skc;
    const unsigned short* gB0 = Bt + (size_t)(n0 + srow) * HID + skc;
    const unsigned short* gB1 = gB0 + 64 * HID;
    f32x4 acc[2][4] = {};
    for (int k0 = 0; k0 < HID; k0 += 32) {
        async16(gA + k0, As + tid*8);
        async16(gB0 + k0, Bs + tid*8);
        async16(gB1 + k0, Bs + 2048 + tid*8);
        __syncthreads();
        const int q8 = (lane >> 4) * 8, l15 = lane & 15;
        bf16x8 af[2], bfr[4];
        #pragma unroll
        for (int mt = 0; mt < 2; ++mt)
            af[mt] = *(const bf16x8*)(As + (wm*32 + mt*16 + l15) * 32 + q8);
        #pragma unroll
        for (int nt = 0; nt < 4; ++nt)
            bfr[nt] = *(const bf16x8*)(Bs + (wn*64 + nt*16 + l15) * 32 + q8);
        #pragma unroll
        for (int mt = 0; mt < 2; ++mt)
            #pragma unroll
            for (int nt = 0; nt < 4; ++nt)
                acc[mt][nt] = __builtin_amdgcn_mfma_f32_16x16x32_bf16(af[mt], bfr[nt], acc[mt][nt], 0, 0, 0);
        __syncthreads();
    }
    const int colL = wn*64 + (lane & 15);
    #pragma unroll
    for (int nt = 0; nt < 4; ++nt) {
        const int col = n0 + colL + nt*16;
        const float bb = b1[(z + 1) * HID + col];
        #pragma unroll
        for (int mt = 0; mt < 2; ++mt)
            #pragma unroll
            for (int r = 0; r < 4; ++r) {
                const int row = m0 + wm*32 + mt*16 + (lane >> 4)*4 + r;
                Yobs[(size_t)z * 65536 + (size_t)row * HID + col] = acc[mt][nt][r] + bb;
            }
    }
}

// ---------------- chain: per-batch serial context chain (one block per b) ----
// Writes Y0all[i-1][b][512] (pre-action first-layer activations, fp32) and
// CTXS[i-1][b][128] (context INPUT to iteration i).
__launch_bounds__(256)
__global__ void chain_kernel(const float* __restrict__ Yobs, const float* __restrict__ W1,
                             const unsigned short* __restrict__ W1Cbf,
                             const unsigned short* __restrict__ W2bf,
                             const unsigned short* __restrict__ W3bf,
                             const float* __restrict__ b2, const float* __restrict__ b3,
                             const float* __restrict__ actions,
                             float* __restrict__ Y0all, float* __restrict__ CTXS) {
    const int b = blockIdx.x, t = threadIdx.x;
    __shared__ float ctx[128], h1[512], h2s[512], part[128];
    if (t < 128) ctx[t] = 0.f;
    __syncthreads();
    for (int i = 1; i <= 6; ++i) {
        if (t < 128) CTXS[(size_t)(i-1)*16384 + b*128 + t] = ctx[t];
        float a = actions[b*ACT + i];
        float fj = floorf((a + 1.0f) * 0.5f * 100.0f);
        fj = fminf(fmaxf(fj, 0.0f), 99.0f);
        // layer1 (ctx part; obs part precomputed in Yobs)
        const int n2 = 2*t;
        float2 yo = *(const float2*)(Yobs + (size_t)(i-1)*65536 + b*512 + n2);
        float acc0 = yo.x, acc1 = yo.y;
        const unsigned int* wp1 = (const unsigned int*)(W1Cbf + (size_t)(i-1)*65536) + t;
        #pragma unroll 4
        for (int k = 0; k < 128; ++k) {
            unsigned int u = wp1[k*256];
            float c = ctx[k];
            acc0 = fmaf(c, __uint_as_float(u << 16), acc0);
            acc1 = fmaf(c, __uint_as_float(u & 0xffff0000u), acc1);
        }
        *(float2*)(Y0all + (size_t)(i-1)*65536 + b*512 + n2) = make_float2(acc0, acc1);
        const float* w1a = W1 + (size_t)i*328192 + 262144;   // row 512 of W1[i]
        h1[n2]   = fmaxf(fmaf(fj, w1a[n2],   acc0), 0.f);
        h1[n2+1] = fmaxf(fmaf(fj, w1a[n2+1], acc1), 0.f);
        __syncthreads();
        // layer2
        acc0 = b2[i*512 + n2]; acc1 = b2[i*512 + n2 + 1];
        const unsigned int* wp2 = (const unsigned int*)(W2bf + (size_t)(i-1)*262144) + t;
        #pragma unroll 4
        for (int k = 0; k < 512; ++k) {
            unsigned int u = wp2[k*256];
            float hv = h1[k];
            acc0 = fmaf(hv, __uint_as_float(u << 16), acc0);
            acc1 = fmaf(hv, __uint_as_float(u & 0xffff0000u), acc1);
        }
        h2s[n2]   = fmaxf(acc0, 0.f);
        h2s[n2+1] = fmaxf(acc1, 0.f);
        __syncthreads();
        // layer3: 128 outputs, split-k over 2 halves
        {
            const int n = t & 127, kh = t >> 7;
            const unsigned short* w3 = W3bf + (size_t)(i-1)*65536 + n;
            float acc = 0.f;
            #pragma unroll 4
            for (int k = kh*256; k < kh*256 + 256; ++k)
                acc = fmaf(h2s[k], __uint_as_float(((unsigned int)w3[k*128]) << 16), acc);
            if (kh) part[n] = acc;
            __syncthreads();
            if (!kh) ctx[n] = acc + part[n] + b3[i*128 + n] + ctx[n];
            __syncthreads();
        }
    }
}

// ---------------- h2all: H2 = bf16(relu(relu(Y0+c*w1a) @ W2 + b2)) -----------
// All 6 iterations batched: 76800 rows, 128x128 tiles, BK=64, A computed on the fly.
__launch_bounds__(256)
__global__ void h2all_kernel(const float* __restrict__ Y0all, const float* __restrict__ W1,
                             const unsigned short* __restrict__ W2T, const float* __restrict__ b2,
                             unsigned short* __restrict__ H2) {
    __shared__ unsigned short As[2][4096];   // [h][row*32+kc], 128 rows
    __shared__ unsigned short Bs[2][4096];
    const int bx = blockIdx.x;               // 0..599
    const int z  = bx / 100;
    const int r0 = bx * 128;                 // global row
    const int r2 = (bx % 100) * 128;         // row within iteration z
    const int n0 = blockIdx.y * 128;
    const int tid = threadIdx.x, lane = tid & 63, wave = tid >> 6;
    const int wm = wave >> 1, wn = wave & 1;
    const int srow = tid >> 2, skc = (tid & 3) * 8;
    const int l15 = lane & 15, q8 = (lane >> 4) * 8;
    // A-fill assignments: rows rA and rA+64, k-chunk kc (==skc)
    const int rA = srow, kc = skc;
    const int rowg1 = r2 + rA, rowg2 = r2 + rA + 64;
    const float c1 = (float)(rowg1 % 100), c2 = (float)(rowg2 % 100);
    const float* y1p = Y0all + (size_t)z*65536 + (size_t)(rowg1/100)*512;
    const float* y2p = Y0all + (size_t)z*65536 + (size_t)(rowg2/100)*512;
    const float* w1a = W1 + (size_t)(z+1)*328192 + 262144;
    const unsigned short* gB0 = W2T + (size_t)z*262144 + (size_t)(n0 + srow)*512 + skc;
    const unsigned short* gB1 = gB0 + 64*512;
    f32x4 acc[4][4] = {};
    for (int k0 = 0; k0 < 512; k0 += 64) {
        #pragma unroll
        for (int h = 0; h < 2; ++h) {
            const int k = k0 + h*32 + kc;
            float4 wv0 = *(const float4*)(w1a + k);
            float4 wv1 = *(const float4*)(w1a + k + 4);
            float4 ya0 = *(const float4*)(y1p + k);
            float4 ya1 = *(const float4*)(y1p + k + 4);
            float4 yb0 = *(const float4*)(y2p + k);
            float4 yb1 = *(const float4*)(y2p + k + 4);
            u16x8 o1, o2;
            o1[0] = f2bf(fmaxf(fmaf(c1, wv0.x, ya0.x), 0.f));
            o1[1] = f2bf(fmaxf(fmaf(c1, wv0.y, ya0.y), 0.f));
            o1[2] = f2bf(fmaxf(fmaf(c1, wv0.z, ya0.z), 0.f));
            o1[3] = f2bf(fmaxf(fmaf(c1, wv0.w, ya0.w), 0.f));
            o1[4] = f2bf(fmaxf(fmaf(c1, wv1.x, ya1.x), 0.f));
            o1[5] = f2bf(fmaxf(fmaf(c1, wv1.y, ya1.y), 0.f));
            o1[6] = f2bf(fmaxf(fmaf(c1, wv1.z, ya1.z), 0.f));
            o1[7] = f2bf(fmaxf(fmaf(c1, wv1.w, ya1.w), 0.f));
            o2[0] = f2bf(fmaxf(fmaf(c2, wv0.x, yb0.x), 0.f));
            o2[1] = f2bf(fmaxf(fmaf(c2, wv0.y, yb0.y), 0.f));
            o2[2] = f2bf(fmaxf(fmaf(c2, wv0.z, yb0.z), 0.f));
            o2[3] = f2bf(fmaxf(fmaf(c2, wv0.w, yb0.w), 0.f));
            o2[4] = f2bf(fmaxf(fmaf(c2, wv1.x, yb1.x), 0.f));
            o2[5] = f2bf(fmaxf(fmaf(c2, wv1.y, yb1.y), 0.f));
            o2[6] = f2bf(fmaxf(fmaf(c2, wv1.z, yb1.z), 0.f));
            o2[7] = f2bf(fmaxf(fmaf(c2, wv1.w, yb1.w), 0.f));
            *(u16x8*)(&As[h][rA*32 + kc]) = o1;
            *(u16x8*)(&As[h][(rA + 64)*32 + kc]) = o2;
        }
        async16(gB0 + k0,      &Bs[0][tid*8]);
        async16(gB1 + k0,      &Bs[0][2048 + tid*8]);
        async16(gB0 + k0 + 32, &Bs[1][tid*8]);
        async16(gB1 + k0 + 32, &Bs[1][2048 + tid*8]);
        __syncthreads();
        #pragma unroll
        for (int h = 0; h < 2; ++h) {
            bf16x8 af[4], bfr[4];
            #pragma unroll
            for (int mt = 0; mt < 4; ++mt)
                af[mt] = *(const bf16x8*)(&As[h][(wm*64 + mt*16 + l15)*32 + q8]);
            #pragma unroll
            for (int nt = 0; nt < 4; ++nt)
                bfr[nt] = *(const bf16x8*)(&Bs[h][(wn*64 + nt*16 + l15)*32 + q8]);
            #pragma unroll
            for (int mt = 0; mt < 4; ++mt)
                #pragma unroll
                for (int nt = 0; nt < 4; ++nt)
                    acc[mt][nt] = __builtin_amdgcn_mfma_f32_16x16x32_bf16(af[mt], bfr[nt], acc[mt][nt], 0, 0, 0);
        }
        __syncthreads();
    }
    #pragma unroll
    for (int nt = 0; nt < 4; ++nt) {
        const int col = n0 + wn*64 + nt*16 + l15;
        const float bb = b2[(z+1)*512 + col];
        #pragma unroll
        for (int mt = 0; mt < 4; ++mt)
            #pragma unroll
            for (int r = 0; r < 4; ++r) {
                const int row = r0 + wm*64 + mt*16 + (lane >> 4)*4 + r;
                H2[(size_t)row * 512 + col] = f2bf(fmaxf(acc[mt][nt][r] + bb, 0.f));
            }
    }
}

// ---------------- gemm3all: CC = H2@W3 + b3 + ctx; q = CC@Wp + bp ------------
// All 6 iterations batched: M=32 tiles, 2400 blocks.
__launch_bounds__(256)
__global__ void gemm3all_kernel(const unsigned short* __restrict__ H2,
                                const unsigned short* __restrict__ W3T,
                                const float* __restrict__ b3, const float* __restrict__ CTXS,
                                const float* __restrict__ Wp, const float* __restrict__ bp,
                                float* __restrict__ q) {
    __shared__ unsigned short As[2][1024];   // 32 rows x 32 k
    __shared__ unsigned short Bs[2][4096];   // 128 n x 32 k
    __shared__ float CCs[32][132];
    __shared__ float qp[32][8];
    const int bx = blockIdx.x;               // 0..2399
    const int z  = bx / 400;
    const int r0 = bx * 32;                  // global H2 row
    const int r2 = (bx % 400) * 32;          // row within iteration z
    const int tid = threadIdx.x, lane = tid & 63, wave = tid >> 6;
    const int wm = wave >> 1, wn = wave & 1;
    const int srow = tid >> 2, skc = (tid & 3) * 8;
    const int l15 = lane & 15, q8 = (lane >> 4) * 8;
    const unsigned short* gB0 = W3T + (size_t)z*65536 + (size_t)srow*512 + skc;
    const unsigned short* gB1 = gB0 + 64*512;
    const unsigned short* gA  = H2 + (size_t)(r0 + srow)*512 + skc;  // valid for tid<128
    f32x4 acc[4] = {};
    for (int k0 = 0; k0 < 512; k0 += 64) {
        if (tid < 128) {
            async16(gA + k0,      &As[0][tid*8]);
            async16(gA + k0 + 32, &As[1][tid*8]);
        }
        async16(gB0 + k0,      &Bs[0][tid*8]);
        async16(gB1 + k0,      &Bs[0][2048 + tid*8]);
        async16(gB0 + k0 + 32, &Bs[1][tid*8]);
        async16(gB1 + k0 + 32, &Bs[1][2048 + tid*8]);
        __syncthreads();
        #pragma unroll
        for (int h = 0; h < 2; ++h) {
            bf16x8 af = *(const bf16x8*)(&As[h][(wm*16 + l15)*32 + q8]);
            #pragma unroll
            for (int nt = 0; nt < 4; ++nt) {
                bf16x8 bfr = *(const bf16x8*)(&Bs[h][(wn*64 + nt*16 + l15)*32 + q8]);
                acc[nt] = __builtin_amdgcn_mfma_f32_16x16x32_bf16(af, bfr, acc[nt], 0, 0, 0);
            }
        }
        __syncthreads();
    }
    #pragma unroll
    for (int nt = 0; nt < 4; ++nt) {
        const int col = wn*64 + nt*16 + l15;
        const float bb = b3[(z+1)*128 + col];
        #pragma unroll
        for (int r = 0; r < 4; ++r) {
            const int rowL = wm*16 + (lane >> 4)*4 + r;
            const int gb = (r2 + rowL) / 100;
            CCs[rowL][col] = acc[nt][r] + bb + CTXS[(size_t)z*16384 + gb*128 + col];
        }
    }
    __syncthreads();
    {
        const int rowL = tid >> 3, seg = tid & 7;
        float s = 0.f;
        #pragma unroll
        for (int j = 0; j < 16; ++j) s += CCs[rowL][seg*16 + j] * Wp[seg*16 + j];
        qp[rowL][seg] = s;
    }
    __syncthreads();
    if (tid < 32) {
        const int gr2 = r2 + tid;
        const int gb = gr2 / 100, gc = gr2 - gb * 100;
        float s = qp[tid][0] + qp[tid][1] + qp[tid][2] + qp[tid][3]
                + qp[tid][4] + qp[tid][5] + qp[tid][6] + qp[tid][7];
        q[gb * QW + z * 100 + gc] = s + bp[0];
    }
}

// ---------------- out[b] = logsumexp([q[b,0:600], zeros(100)]) ---------------
__global__ void lse_kernel(const float* __restrict__ q, float* __restrict__ out) {
    __shared__ float red[256];
    int b = blockIdx.x, t = threadIdx.x;
    float m = 0.0f;   // zero tail participates in the max
    for (int k = t; k < QW; k += 256) m = fmaxf(m, q[b*QW + k]);
    red[t] = m; __syncthreads();
    for (int s = 128; s > 0; s >>= 1) { if (t < s) red[t] = fmaxf(red[t], red[t+s]); __syncthreads(); }
    m = red[0]; __syncthreads();
    float sum = 0.0f;
    for (int k = t; k < QW; k += 256) sum += expf(q[b*QW + k] - m);
    red[t] = sum; __syncthreads();
    for (int s = 128; s > 0; s >>= 1) { if (t < s) red[t] += red[t+s]; __syncthreads(); }
    if (t == 0) out[b] = logf(red[0] + 100.0f * expf(-m)) + m;
}

extern "C" void kernel_launch(void* const* d_in, const int* in_sizes, int n_in,
                              void* d_out, int out_size, void* d_ws, size_t ws_size,
                              hipStream_t stream) {
    const float* obs     = (const float*)d_in[0];
    const float* actions = (const float*)d_in[1];
    const float* W1      = (const float*)d_in[2];
    const float* b1      = (const float*)d_in[3];
    const float* W2      = (const float*)d_in[4];
    const float* b2      = (const float*)d_in[5];
    const float* W3      = (const float*)d_in[6];
    const float* b3      = (const float*)d_in[7];
    const float* Wp      = (const float*)d_in[8];
    const float* bp      = (const float*)d_in[9];
    float* out = (float*)d_out;
    float* ws  = (float*)d_ws;

    // workspace layout (float offsets)
    unsigned short* obs_bf = (unsigned short*)(ws);            // 65536 us = 32768 f
    unsigned short* W1AT   = (unsigned short*)(ws + 32768);    // 1572864 us = 786432 f
    unsigned short* W2T    = (unsigned short*)(ws + 819200);   // 786432 f
    unsigned short* W3T    = (unsigned short*)(ws + 1605632);  // 196608 f
    unsigned short* W1Cbf  = (unsigned short*)(ws + 1802240);  // 196608 f
    unsigned short* W2bf   = (unsigned short*)(ws + 1998848);  // 786432 f
    unsigned short* W3bf   = (unsigned short*)(ws + 2785280);  // 196608 f
    float* Yobs  = ws + 2981888;                               // 393216 f
    float* Y0all = ws + 3375104;                               // 393216 f
    float* CTXS  = ws + 3768320;                               // 98304 f
    float* q     = ws + 3866624;                               // 76800 f
    unsigned short* H2 = (unsigned short*)(ws + 3943424);      // 39321600 us = 19660800 f

    cvt_kernel<<<2368, 256, 0, stream>>>(obs, W1, W2, W3, obs_bf, W1Cbf, W2bf, W3bf);
    prep_transpose<<<dim3(16,16,18), dim3(32,8), 0, stream>>>(W1, W2, W3, W1AT, W2T, W3T);
    yobs_kernel<<<dim3(2,4,6), 256, 0, stream>>>(obs_bf, W1AT, b1, Yobs);
    chain_kernel<<<BATCH, 256, 0, stream>>>(Yobs, W1, W1Cbf, W2bf, W3bf, b2, b3, actions, Y0all, CTXS);
    h2all_kernel<<<dim3(600, 4), 256, 0, stream>>>(Y0all, W1, W2T, b2, H2);
    gemm3all_kernel<<<2400, 256, 0, stream>>>(H2, W3T, b3, CTXS, Wp, bp, q);
    lse_kernel<<<BATCH, 256, 0, stream>>>(q, out);
}

// Round 5
// 263.335 us; speedup vs baseline: 2.0848x; 2.0848x over previous
//
#include <hip/hip_runtime.h>
#include <math.h>

#define BATCH 128
#define ACT 7
#define NC 100
#define CTXD 128
#define HID 512
#define QW 600               // q width (cols 600..699 of reference are exactly 0)

typedef __attribute__((ext_vector_type(8))) __bf16 bf16x8;
typedef __attribute__((ext_vector_type(4))) float f32x4;
typedef __attribute__((ext_vector_type(8))) unsigned short u16x8;
typedef __attribute__((ext_vector_type(4))) unsigned short u16x4;

__device__ __forceinline__ unsigned short f2bf(float f) {
    union { float f; unsigned int u; } v; v.f = f;
    unsigned int u = v.u;
    return (unsigned short)((u + 0x7fffu + ((u >> 16) & 1u)) >> 16);
}

// async global->LDS, 16B per lane. LDS dest = wave-uniform base + lane*16.
__device__ __forceinline__ void async16(const void* g, void* l) {
    __builtin_amdgcn_global_load_lds(
        (const __attribute__((address_space(1))) unsigned int*)(uintptr_t)g,
        (__attribute__((address_space(3))) unsigned int*)(unsigned int)(uintptr_t)l,
        16, 0, 0);
}

// ---------------- cvt: fp32 -> bf16 row-major copies -------------------------
__global__ void cvt_kernel(const float* __restrict__ obs, const float* __restrict__ W1,
                           const float* __restrict__ W2, const float* __restrict__ W3,
                           unsigned short* __restrict__ obs_bf, unsigned short* __restrict__ W1Cbf,
                           unsigned short* __restrict__ W2bf, unsigned short* __restrict__ W3bf) {
    const int e = (blockIdx.x * 256 + threadIdx.x) * 4;   // grid covers 2424832 elems
    const float* src; unsigned short* dst;
    if (e < 65536)        { src = obs + e; dst = obs_bf + e; }
    else if (e < 458752)  { int f = e - 65536; int i = f >> 16; int rem = f & 65535;
                            src = W1 + (size_t)(i + 1) * 328192 + 513*512 + rem; dst = W1Cbf + f; }
    else if (e < 2031616) { int f = e - 458752; src = W2 + 262144 + f; dst = W2bf + f; }
    else                  { int f = e - 2031616; src = W3 + 65536 + f; dst = W3bf + f; }
    float4 v = *(const float4*)src;
    u16x4 o; o[0] = f2bf(v.x); o[1] = f2bf(v.y); o[2] = f2bf(v.z); o[3] = f2bf(v.w);
    *(u16x4*)dst = o;
}

// ---------------- transpose+convert: W1AT / W2T / W3T ------------------------
__global__ void prep_transpose(const float* __restrict__ W1, const float* __restrict__ W2,
                               const float* __restrict__ W3,
                               unsigned short* __restrict__ W1AT, unsigned short* __restrict__ W2T,
                               unsigned short* __restrict__ W3T) {
    __shared__ float tile[32][33];
    const int z = blockIdx.z;
    const float* ip; unsigned short* op; int Cn;
    if (z < 6)       { ip = W1 + (size_t)(z + 1) * 328192; op = W1AT + (size_t)z * 262144; Cn = 512; }
    else if (z < 12) { int i = z - 6;  ip = W2 + (size_t)(i + 1) * 262144; op = W2T + (size_t)i * 262144; Cn = 512; }
    else             { int i = z - 12; ip = W3 + (size_t)(i + 1) * 65536;  op = W3T + (size_t)i * 65536;  Cn = 128;
                       if (blockIdx.y >= 4) return; }
    const int r0 = blockIdx.x * 32, c0 = blockIdx.y * 32;
    const int tx = threadIdx.x, ty = threadIdx.y;  // 32 x 8
    #pragma unroll
    for (int j = 0; j < 32; j += 8)
        tile[ty + j][tx] = ip[(size_t)(r0 + ty + j) * Cn + c0 + tx];
    __syncthreads();
    #pragma unroll
    for (int j = 0; j < 32; j += 8)
        op[(size_t)(c0 + ty + j) * 512 + r0 + tx] = f2bf(tile[tx][ty + j]);
}

// ---------------- Yobs[z][b][h] = obs@W1A[z+1] + b1[z+1] ---------------------
__launch_bounds__(256)
__global__ void yobs_kernel(const unsigned short* __restrict__ A,      // obs_bf [128][512]
                            const unsigned short* __restrict__ BtAll,  // W1AT [6][512][512]
                            const float* __restrict__ b1,
                            float* __restrict__ Yobs) {
    __shared__ unsigned short As[64*32];
    __shared__ unsigned short Bs[128*32];
    const int m0 = blockIdx.x * 64;
    const int n0 = blockIdx.y * 128;
    const int z  = blockIdx.z;
    const unsigned short* Bt = BtAll + (size_t)z * 262144;
    const int tid = threadIdx.x, lane = tid & 63, wave = tid >> 6;
    const int wm = wave >> 1, wn = wave & 1;
    const int srow = tid >> 2, skc = (tid & 3) * 8;
    const unsigned short* gA  = A  + (size_t)(m0 + srow) * HID + skc;
    const unsigned short* gB0 = Bt + (size_t)(n0 + srow) * HID + skc;
    const unsigned short* gB1 = gB0 + 64 * HID;
    f32x4 acc[2][4] = {};
    for (int k0 = 0; k0 < HID; k0 += 32) {
        async16(gA + k0, As + tid*8);
        async16(gB0 + k0, Bs + tid*8);
        async16(gB1 + k0, Bs + 2048 + tid*8);
        __syncthreads();
        const int q8 = (lane >> 4) * 8, l15 = lane & 15;
        bf16x8 af[2], bfr[4];
        #pragma unroll
        for (int mt = 0; mt < 2; ++mt)
            af[mt] = *(const bf16x8*)(As + (wm*32 + mt*16 + l15) * 32 + q8);
        #pragma unroll
        for (int nt = 0; nt < 4; ++nt)
            bfr[nt] = *(const bf16x8*)(Bs + (wn*64 + nt*16 + l15) * 32 + q8);
        #pragma unroll
        for (int mt = 0; mt < 2; ++mt)
            #pragma unroll
            for (int nt = 0; nt < 4; ++nt)
                acc[mt][nt] = __builtin_amdgcn_mfma_f32_16x16x32_bf16(af[mt], bfr[nt], acc[mt][nt], 0, 0, 0);
        __syncthreads();
    }
    const int colL = wn*64 + (lane & 15);
    #pragma unroll
    for (int nt = 0; nt < 4; ++nt) {
        const int col = n0 + colL + nt*16;
        const float bb = b1[(z + 1) * HID + col];
        #pragma unroll
        for (int mt = 0; mt < 2; ++mt)
            #pragma unroll
            for (int r = 0; r < 4; ++r) {
                const int row = m0 + wm*32 + mt*16 + (lane >> 4)*4 + r;
                Yobs[(size_t)z * 65536 + (size_t)row * HID + col] = acc[mt][nt][r] + bb;
            }
    }
}

// ---------------- chain: per-batch serial context chain, 1024 thr, split-K ---
// Writes Y0all[i-1][b][512] and CTXS[i-1][b][128] (context INPUT to iter i).
__launch_bounds__(1024)
__global__ void chain_kernel(const float* __restrict__ Yobs, const float* __restrict__ W1,
                             const unsigned short* __restrict__ W1Cbf,
                             const unsigned short* __restrict__ W2bf,
                             const unsigned short* __restrict__ W3bf,
                             const float* __restrict__ b2, const float* __restrict__ b3,
                             const float* __restrict__ actions,
                             float* __restrict__ Y0all, float* __restrict__ CTXS) {
    const int b = blockIdx.x, t = threadIdx.x;
    __shared__ float ctx[128], h1[512], h2s[512];
    __shared__ float part[2048];      // layer1/2: [4][512]; layer3: [16][128]
    const int pair = t & 255, kq = t >> 8;      // layers 1,2
    const int pair3 = t & 63, kq3 = t >> 6;     // layer 3
    if (t < 128) ctx[t] = 0.f;
    __syncthreads();
    for (int i = 1; i <= 6; ++i) {
        if (t < 128) CTXS[(size_t)(i-1)*16384 + b*128 + t] = ctx[t];
        const float a = actions[b*ACT + i];
        float fj = floorf((a + 1.0f) * 50.0f);
        fj = fminf(fmaxf(fj, 0.0f), 99.0f);
        // ---- layer1 ctx part: 256 pairs x 4 k-quarters (32 k each) ----
        {
            const unsigned int* wp1 = (const unsigned int*)(W1Cbf + (size_t)(i-1)*65536) + pair;
            float acc0 = 0.f, acc1 = 0.f;
            #pragma unroll 8
            for (int k = kq*32; k < kq*32 + 32; ++k) {
                unsigned int u = wp1[k*256];
                float c = ctx[k];
                acc0 = fmaf(c, __uint_as_float(u << 16), acc0);
                acc1 = fmaf(c, __uint_as_float(u & 0xffff0000u), acc1);
            }
            *(float2*)(&part[kq*512 + 2*pair]) = make_float2(acc0, acc1);
        }
        __syncthreads();
        if (t < 256) {
            const int n2 = 2*t;
            float2 p0 = *(const float2*)(&part[n2]);
            float2 p1 = *(const float2*)(&part[512 + n2]);
            float2 p2 = *(const float2*)(&part[1024 + n2]);
            float2 p3 = *(const float2*)(&part[1536 + n2]);
            float2 yo = *(const float2*)(Yobs + (size_t)(i-1)*65536 + b*512 + n2);
            float y0a = yo.x + p0.x + p1.x + p2.x + p3.x;
            float y0b = yo.y + p0.y + p1.y + p2.y + p3.y;
            *(float2*)(Y0all + (size_t)(i-1)*65536 + b*512 + n2) = make_float2(y0a, y0b);
            const float* w1a = W1 + (size_t)i*328192 + 262144;   // row 512 of W1[i]
            float2 wv = *(const float2*)(w1a + n2);
            h1[n2]   = fmaxf(fmaf(fj, wv.x, y0a), 0.f);
            h1[n2+1] = fmaxf(fmaf(fj, wv.y, y0b), 0.f);
        }
        __syncthreads();
        // ---- layer2: 256 pairs x 4 k-quarters (128 k each) ----
        {
            const unsigned int* wp2 = (const unsigned int*)(W2bf + (size_t)(i-1)*262144) + pair;
            float acc0 = 0.f, acc1 = 0.f;
            #pragma unroll 8
            for (int k = kq*128; k < kq*128 + 128; ++k) {
                unsigned int u = wp2[k*256];
                float hv = h1[k];
                acc0 = fmaf(hv, __uint_as_float(u << 16), acc0);
                acc1 = fmaf(hv, __uint_as_float(u & 0xffff0000u), acc1);
            }
            *(float2*)(&part[kq*512 + 2*pair]) = make_float2(acc0, acc1);
        }
        __syncthreads();
        if (t < 256) {
            const int n2 = 2*t;
            float2 p0 = *(const float2*)(&part[n2]);
            float2 p1 = *(const float2*)(&part[512 + n2]);
            float2 p2 = *(const float2*)(&part[1024 + n2]);
            float2 p3 = *(const float2*)(&part[1536 + n2]);
            float2 bb = *(const float2*)(b2 + i*512 + n2);
            h2s[n2]   = fmaxf(p0.x + p1.x + p2.x + p3.x + bb.x, 0.f);
            h2s[n2+1] = fmaxf(p0.y + p1.y + p2.y + p3.y + bb.y, 0.f);
        }
        __syncthreads();
        // ---- layer3: 64 pairs x 16 k-groups (32 k each) ----
        {
            const unsigned int* wp3 = (const unsigned int*)(W3bf + (size_t)(i-1)*65536) + pair3;
            float acc0 = 0.f, acc1 = 0.f;
            #pragma unroll 8
            for (int k = kq3*32; k < kq3*32 + 32; ++k) {
                unsigned int u = wp3[k*64];
                float hv = h2s[k];
                acc0 = fmaf(hv, __uint_as_float(u << 16), acc0);
                acc1 = fmaf(hv, __uint_as_float(u & 0xffff0000u), acc1);
            }
            *(float2*)(&part[kq3*128 + 2*pair3]) = make_float2(acc0, acc1);
        }
        __syncthreads();
        if (t < 128) {
            float s = 0.f;
            #pragma unroll
            for (int qg = 0; qg < 16; ++qg) s += part[qg*128 + t];
            ctx[t] = s + b3[i*128 + t] + ctx[t];
        }
        __syncthreads();
    }
}

// ---------------- h2all: H2 = bf16(relu(relu(Y0+c*w1a) @ W2 + b2)) -----------
// All 6 iterations batched: 76800 rows, 128x128 tiles, BK=64, A computed on the fly.
__launch_bounds__(256)
__global__ void h2all_kernel(const float* __restrict__ Y0all, const float* __restrict__ W1,
                             const unsigned short* __restrict__ W2T, const float* __restrict__ b2,
                             unsigned short* __restrict__ H2) {
    __shared__ unsigned short As[2][4096];   // [h][row*32+kc], 128 rows
    __shared__ unsigned short Bs[2][4096];
    const int bx = blockIdx.x;               // 0..599
    const int z  = bx / 100;
    const int r0 = bx * 128;                 // global row
    const int r2 = (bx % 100) * 128;         // row within iteration z
    const int n0 = blockIdx.y * 128;
    const int tid = threadIdx.x, lane = tid & 63, wave = tid >> 6;
    const int wm = wave >> 1, wn = wave & 1;
    const int srow = tid >> 2, skc = (tid & 3) * 8;
    const int l15 = lane & 15, q8 = (lane >> 4) * 8;
    const int rA = srow, kc = skc;
    const int rowg1 = r2 + rA, rowg2 = r2 + rA + 64;
    const float c1 = (float)(rowg1 % 100), c2 = (float)(rowg2 % 100);
    const float* y1p = Y0all + (size_t)z*65536 + (size_t)(rowg1/100)*512;
    const float* y2p = Y0all + (size_t)z*65536 + (size_t)(rowg2/100)*512;
    const float* w1a = W1 + (size_t)(z+1)*328192 + 262144;
    const unsigned short* gB0 = W2T + (size_t)z*262144 + (size_t)(n0 + srow)*512 + skc;
    const unsigned short* gB1 = gB0 + 64*512;
    f32x4 acc[4][4] = {};
    for (int k0 = 0; k0 < 512; k0 += 64) {
        #pragma unroll
        for (int h = 0; h < 2; ++h) {
            const int k = k0 + h*32 + kc;
            float4 wv0 = *(const float4*)(w1a + k);
            float4 wv1 = *(const float4*)(w1a + k + 4);
            float4 ya0 = *(const float4*)(y1p + k);
            float4 ya1 = *(const float4*)(y1p + k + 4);
            float4 yb0 = *(const float4*)(y2p + k);
            float4 yb1 = *(const float4*)(y2p + k + 4);
            u16x8 o1, o2;
            o1[0] = f2bf(fmaxf(fmaf(c1, wv0.x, ya0.x), 0.f));
            o1[1] = f2bf(fmaxf(fmaf(c1, wv0.y, ya0.y), 0.f));
            o1[2] = f2bf(fmaxf(fmaf(c1, wv0.z, ya0.z), 0.f));
            o1[3] = f2bf(fmaxf(fmaf(c1, wv0.w, ya0.w), 0.f));
            o1[4] = f2bf(fmaxf(fmaf(c1, wv1.x, ya1.x), 0.f));
            o1[5] = f2bf(fmaxf(fmaf(c1, wv1.y, ya1.y), 0.f));
            o1[6] = f2bf(fmaxf(fmaf(c1, wv1.z, ya1.z), 0.f));
            o1[7] = f2bf(fmaxf(fmaf(c1, wv1.w, ya1.w), 0.f));
            o2[0] = f2bf(fmaxf(fmaf(c2, wv0.x, yb0.x), 0.f));
            o2[1] = f2bf(fmaxf(fmaf(c2, wv0.y, yb0.y), 0.f));
            o2[2] = f2bf(fmaxf(fmaf(c2, wv0.z, yb0.z), 0.f));
            o2[3] = f2bf(fmaxf(fmaf(c2, wv0.w, yb0.w), 0.f));
            o2[4] = f2bf(fmaxf(fmaf(c2, wv1.x, yb1.x), 0.f));
            o2[5] = f2bf(fmaxf(fmaf(c2, wv1.y, yb1.y), 0.f));
            o2[6] = f2bf(fmaxf(fmaf(c2, wv1.z, yb1.z), 0.f));
            o2[7] = f2bf(fmaxf(fmaf(c2, wv1.w, yb1.w), 0.f));
            *(u16x8*)(&As[h][rA*32 + kc]) = o1;
            *(u16x8*)(&As[h][(rA + 64)*32 + kc]) = o2;
        }
        async16(gB0 + k0,      &Bs[0][tid*8]);
        async16(gB1 + k0,      &Bs[0][2048 + tid*8]);
        async16(gB0 + k0 + 32, &Bs[1][tid*8]);
        async16(gB1 + k0 + 32, &Bs[1][2048 + tid*8]);
        __syncthreads();
        #pragma unroll
        for (int h = 0; h < 2; ++h) {
            bf16x8 af[4], bfr[4];
            #pragma unroll
            for (int mt = 0; mt < 4; ++mt)
                af[mt] = *(const bf16x8*)(&As[h][(wm*64 + mt*16 + l15)*32 + q8]);
            #pragma unroll
            for (int nt = 0; nt < 4; ++nt)
                bfr[nt] = *(const bf16x8*)(&Bs[h][(wn*64 + nt*16 + l15)*32 + q8]);
            #pragma unroll
            for (int mt = 0; mt < 4; ++mt)
                #pragma unroll
                for (int nt = 0; nt < 4; ++nt)
                    acc[mt][nt] = __builtin_amdgcn_mfma_f32_16x16x32_bf16(af[mt], bfr[nt], acc[mt][nt], 0, 0, 0);
        }
        __syncthreads();
    }
    #pragma unroll
    for (int nt = 0; nt < 4; ++nt) {
        const int col = n0 + wn*64 + nt*16 + l15;
        const float bb = b2[(z+1)*512 + col];
        #pragma unroll
        for (int mt = 0; mt < 4; ++mt)
            #pragma unroll
            for (int r = 0; r < 4; ++r) {
                const int row = r0 + wm*64 + mt*16 + (lane >> 4)*4 + r;
                H2[(size_t)row * 512 + col] = f2bf(fmaxf(acc[mt][nt][r] + bb, 0.f));
            }
    }
}

// ---------------- gemm3all: CC = H2@W3 + b3 + ctx; q = CC@Wp + bp ------------
__launch_bounds__(256)
__global__ void gemm3all_kernel(const unsigned short* __restrict__ H2,
                                const unsigned short* __restrict__ W3T,
                                const float* __restrict__ b3, const float* __restrict__ CTXS,
                                const float* __restrict__ Wp, const float* __restrict__ bp,
                                float* __restrict__ q) {
    __shared__ unsigned short As[2][1024];   // 32 rows x 32 k
    __shared__ unsigned short Bs[2][4096];   // 128 n x 32 k
    __shared__ float CCs[32][132];
    __shared__ float qp[32][8];
    const int bx = blockIdx.x;               // 0..2399
    const int z  = bx / 400;
    const int r0 = bx * 32;                  // global H2 row
    const int r2 = (bx % 400) * 32;          // row within iteration z
    const int tid = threadIdx.x, lane = tid & 63, wave = tid >> 6;
    const int wm = wave >> 1, wn = wave & 1;
    const int srow = tid >> 2, skc = (tid & 3) * 8;
    const int l15 = lane & 15, q8 = (lane >> 4) * 8;
    const unsigned short* gB0 = W3T + (size_t)z*65536 + (size_t)srow*512 + skc;
    const unsigned short* gB1 = gB0 + 64*512;
    const unsigned short* gA  = H2 + (size_t)(r0 + srow)*512 + skc;  // valid for tid<128
    f32x4 acc[4] = {};
    for (int k0 = 0; k0 < 512; k0 += 64) {
        if (tid < 128) {
            async16(gA + k0,      &As[0][tid*8]);
            async16(gA + k0 + 32, &As[1][tid*8]);
        }
        async16(gB0 + k0,      &Bs[0][tid*8]);
        async16(gB1 + k0,      &Bs[0][2048 + tid*8]);
        async16(gB0 + k0 + 32, &Bs[1][tid*8]);
        async16(gB1 + k0 + 32, &Bs[1][2048 + tid*8]);
        __syncthreads();
        #pragma unroll
        for (int h = 0; h < 2; ++h) {
            bf16x8 af = *(const bf16x8*)(&As[h][(wm*16 + l15)*32 + q8]);
            #pragma unroll
            for (int nt = 0; nt < 4; ++nt) {
                bf16x8 bfr = *(const bf16x8*)(&Bs[h][(wn*64 + nt*16 + l15)*32 + q8]);
                acc[nt] = __builtin_amdgcn_mfma_f32_16x16x32_bf16(af, bfr, acc[nt], 0, 0, 0);
            }
        }
        __syncthreads();
    }
    #pragma unroll
    for (int nt = 0; nt < 4; ++nt) {
        const int col = wn*64 + nt*16 + l15;
        const float bb = b3[(z+1)*128 + col];
        #pragma unroll
        for (int r = 0; r < 4; ++r) {
            const int rowL = wm*16 + (lane >> 4)*4 + r;
            const int gb = (r2 + rowL) / 100;
            CCs[rowL][col] = acc[nt][r] + bb + CTXS[(size_t)z*16384 + gb*128 + col];
        }
    }
    __syncthreads();
    {
        const int rowL = tid >> 3, seg = tid & 7;
        float s = 0.f;
        #pragma unroll
        for (int j = 0; j < 16; ++j) s += CCs[rowL][seg*16 + j] * Wp[seg*16 + j];
        qp[rowL][seg] = s;
    }
    __syncthreads();
    if (tid < 32) {
        const int gr2 = r2 + tid;
        const int gb = gr2 / 100, gc = gr2 - gb * 100;
        float s = qp[tid][0] + qp[tid][1] + qp[tid][2] + qp[tid][3]
                + qp[tid][4] + qp[tid][5] + qp[tid][6] + qp[tid][7];
        q[gb * QW + z * 100 + gc] = s + bp[0];
    }
}

// ---------------- out[b] = logsumexp([q[b,0:600], zeros(100)]) ---------------
__global__ void lse_kernel(const float* __restrict__ q, float* __restrict__ out) {
    __shared__ float red[256];
    int b = blockIdx.x, t = threadIdx.x;
    float m = 0.0f;   // zero tail participates in the max
    for (int k = t; k < QW; k += 256) m = fmaxf(m, q[b*QW + k]);
    red[t] = m; __syncthreads();
    for (int s = 128; s > 0; s >>= 1) { if (t < s) red[t] = fmaxf(red[t], red[t+s]); __syncthreads(); }
    m = red[0]; __syncthreads();
    float sum = 0.0f;
    for (int k = t; k < QW; k += 256) sum += expf(q[b*QW + k] - m);
    red[t] = sum; __syncthreads();
    for (int s = 128; s > 0; s >>= 1) { if (t < s) red[t] += red[t+s]; __syncthreads(); }
    if (t == 0) out[b] = logf(red[0] + 100.0f * expf(-m)) + m;
}

extern "C" void kernel_launch(void* const* d_in, const int* in_sizes, int n_in,
                              void* d_out, int out_size, void* d_ws, size_t ws_size,
                              hipStream_t stream) {
    const float* obs     = (const float*)d_in[0];
    const float* actions = (const float*)d_in[1];
    const float* W1      = (const float*)d_in[2];
    const float* b1      = (const float*)d_in[3];
    const float* W2      = (const float*)d_in[4];
    const float* b2      = (const float*)d_in[5];
    const float* W3      = (const float*)d_in[6];
    const float* b3      = (const float*)d_in[7];
    const float* Wp      = (const float*)d_in[8];
    const float* bp      = (const float*)d_in[9];
    float* out = (float*)d_out;
    float* ws  = (float*)d_ws;

    // workspace layout (float offsets)
    unsigned short* obs_bf = (unsigned short*)(ws);            // 32768 f
    unsigned short* W1AT   = (unsigned short*)(ws + 32768);    // 786432 f
    unsigned short* W2T    = (unsigned short*)(ws + 819200);   // 786432 f
    unsigned short* W3T    = (unsigned short*)(ws + 1605632);  // 196608 f
    unsigned short* W1Cbf  = (unsigned short*)(ws + 1802240);  // 196608 f
    unsigned short* W2bf   = (unsigned short*)(ws + 1998848);  // 786432 f
    unsigned short* W3bf   = (unsigned short*)(ws + 2785280);  // 196608 f
    float* Yobs  = ws + 2981888;                               // 393216 f
    float* Y0all = ws + 3375104;                               // 393216 f
    float* CTXS  = ws + 3768320;                               // 98304 f
    float* q     = ws + 3866624;                               // 76800 f
    unsigned short* H2 = (unsigned short*)(ws + 3943424);      // 19660800 f

    cvt_kernel<<<2368, 256, 0, stream>>>(obs, W1, W2, W3, obs_bf, W1Cbf, W2bf, W3bf);
    prep_transpose<<<dim3(16,16,18), dim3(32,8), 0, stream>>>(W1, W2, W3, W1AT, W2T, W3T);
    yobs_kernel<<<dim3(2,4,6), 256, 0, stream>>>(obs_bf, W1AT, b1, Yobs);
    chain_kernel<<<BATCH, 1024, 0, stream>>>(Yobs, W1, W1Cbf, W2bf, W3bf, b2, b3, actions, Y0all, CTXS);
    h2all_kernel<<<dim3(600, 4), 256, 0, stream>>>(Y0all, W1, W2T, b2, H2);
    gemm3all_kernel<<<2400, 256, 0, stream>>>(H2, W3T, b3, CTXS, Wp, bp, q);
    lse_kernel<<<BATCH, 256, 0, stream>>>(q, out);
}